// Round 2
// baseline (2442.547 us; speedup 1.0000x reference)
//
#include <hip/hip_runtime.h>
#include <hip/hip_bf16.h>

#define DEV __device__ __forceinline__

typedef __attribute__((ext_vector_type(8))) short bf16x8_t;
typedef __attribute__((ext_vector_type(4))) float f32x4_t;

constexpr int cB = 4, cC = 256, cH = 256, cW = 128, cHN = 8, cHS = 32;
constexpr int cM = cB * cH * cW;  // 131072 rows

DEV float bfu(unsigned int b16) { union { unsigned int u; float f; } v; v.u = b16 << 16; return v.f; }
DEV unsigned short f2bb(float f) { union { __hip_bfloat16 h; unsigned short u; } v; v.h = __float2bfloat16(f); return v.u; }

// ---------------- weight transpose + fp32->bf16 ----------------
__global__ __launch_bounds__(256) void transpose_bf16(const float* __restrict__ src,
                                                      __hip_bfloat16* __restrict__ dst,
                                                      int R, int Ccol) {
  int idx = blockIdx.x * 256 + threadIdx.x;
  if (idx < R * Ccol) {
    int r = idx / Ccol, c = idx - r * Ccol;
    dst[c * R + r] = __float2bfloat16(src[idx]);
  }
}

// ---------------- fused grouped-proj + RoPE + softpick attention ----------------
// one block per (b, h, g); 256 threads
__global__ __launch_bounds__(256) void attn_kernel(
    const float* __restrict__ left, const float* __restrict__ right,
    const float* __restrict__ qw, const float* __restrict__ kw, const float* __restrict__ vw,
    __hip_bfloat16* __restrict__ att_out)
{
  __shared__ __align__(16) char smem[73728];
  float* Xl = (float*)smem;                                 // [32][128] fp32
  float* Xr = Xl + 4096;                                    // [32][128] fp32
  unsigned short* S = (unsigned short*)smem;                // [128][132] bf16 bits (aliases Xl/Xr)
  __hip_bfloat16* qs = (__hip_bfloat16*)(smem + 33792);     // [128][36]
  __hip_bfloat16* ks = qs + 128 * 36;                       // [128][36]
  __hip_bfloat16* vs = ks + 128 * 36;                       // [128][36]
  float* wqs = (float*)(smem + 61440);                      // [32][32]
  float* wks = wqs + 1024;
  float* wvs = wks + 1024;

  const int t = threadIdx.x;
  const int g = blockIdx.x & 7;
  const int h = (blockIdx.x >> 3) & 255;
  const int b = blockIdx.x >> 11;

  const size_t HW = (size_t)cH * cW;
  const float* lbase = left  + ((size_t)(b * cC + g * cHS) * cH + h) * cW;
  const float* rbase = right + ((size_t)(b * cC + g * cHS) * cH + h) * cW;
  for (int j = t; j < 4096; j += 256) {
    int i = j >> 7, w = j & 127;
    Xl[j] = lbase[i * HW + w];
    Xr[j] = rbase[i * HW + w];
  }
  const float* qwg = qw + g * 1024;
  const float* kwg = kw + g * 1024;
  const float* vwg = vw + g * 1024;
  for (int j = t; j < 1024; j += 256) { wqs[j] = qwg[j]; wks[j] = kwg[j]; wvs[j] = vwg[j]; }
  __syncthreads();

  // phase 2: per-position grouped projection + RoPE; write bf16 q,k,v tiles
  {
    const int w = t & 127, oh = t >> 7;
    float xl[32], xr[32];
#pragma unroll
    for (int i = 0; i < 32; ++i) { xl[i] = Xl[i * 128 + w]; xr[i] = Xr[i * 128 + w]; }
    const float scale = 0.17677669529663687f;  // 1/sqrt(32), folded into q
#pragma unroll
    for (int p = 0; p < 8; ++p) {
      int o1 = oh * 8 + p, o2 = o1 + 16;
      float q1 = 0, q2 = 0, k1 = 0, k2 = 0, v1 = 0, v2 = 0;
      const float* wq1 = wqs + o1 * 32; const float* wq2 = wqs + o2 * 32;
      const float* wk1 = wks + o1 * 32; const float* wk2 = wks + o2 * 32;
      const float* wv1 = wvs + o1 * 32; const float* wv2 = wvs + o2 * 32;
#pragma unroll
      for (int i = 0; i < 32; ++i) {
        q1 += wq1[i] * xl[i]; q2 += wq2[i] * xl[i];
        k1 += wk1[i] * xr[i]; k2 += wk2[i] * xr[i];
        v1 += wv1[i] * xr[i]; v2 += wv2[i] * xr[i];
      }
      // inv_freq = 100^(-o1/16) = exp(-o1 * ln(100)/16)
      float inv = expf((float)o1 * -0.28782313662425572f);
      float ang = (float)w * inv;
      float sn = sinf(ang), cs = cosf(ang);
      qs[w * 36 + o1] = __float2bfloat16((q1 * cs - q2 * sn) * scale);
      qs[w * 36 + o2] = __float2bfloat16((q2 * cs + q1 * sn) * scale);
      ks[w * 36 + o1] = __float2bfloat16(k1 * cs - k2 * sn);
      ks[w * 36 + o2] = __float2bfloat16(k2 * cs + k1 * sn);
      vs[w * 36 + o1] = __float2bfloat16(v1);
      vs[w * 36 + o2] = __float2bfloat16(v2);
    }
  }
  __syncthreads();

  const int wq = t >> 1, half = t & 1;
  // phase 3: S = q.k^T (half row per thread) + softpick
  {
    float qrow[32];
    const uint2* qp = (const uint2*)(qs + wq * 36);
#pragma unroll
    for (int c = 0; c < 8; ++c) {
      uint2 u = qp[c];
      qrow[c * 4 + 0] = bfu(u.x & 0xffff); qrow[c * 4 + 1] = bfu(u.x >> 16);
      qrow[c * 4 + 2] = bfu(u.y & 0xffff); qrow[c * 4 + 3] = bfu(u.y >> 16);
    }
    float sv[64];
#pragma unroll
    for (int j = 0; j < 64; ++j) {
      const uint2* kp = (const uint2*)(ks + (half * 64 + j) * 36);
      float acc = 0.f;
#pragma unroll
      for (int c = 0; c < 8; ++c) {
        uint2 u = kp[c];
        acc += qrow[c * 4 + 0] * bfu(u.x & 0xffff) + qrow[c * 4 + 1] * bfu(u.x >> 16)
             + qrow[c * 4 + 2] * bfu(u.y & 0xffff) + qrow[c * 4 + 3] * bfu(u.y >> 16);
      }
      sv[j] = acc;
    }
    float m = sv[0];
#pragma unroll
    for (int j = 1; j < 64; ++j) m = fmaxf(m, sv[j]);
    m = fmaxf(m, __shfl_xor(m, 1));
    float em = expf(-m);
    float ssum = 0.f;
#pragma unroll
    for (int j = 0; j < 64; ++j) { float e = expf(sv[j] - m) - em; sv[j] = e; ssum += fabsf(e); }
    ssum += __shfl_xor(ssum, 1);
    float dinv = 1.0f / (ssum + 1e-6f);
    unsigned short* srow = S + wq * 132 + half * 64;
#pragma unroll
    for (int j = 0; j < 64; ++j) srow[j] = f2bb(fmaxf(sv[j], 0.f) * dinv);
  }
  __syncthreads();

  // phase 4: O = att @ v (16 output dims per thread)
  {
    const int dh = half;
    float o[16];
#pragma unroll
    for (int d = 0; d < 16; ++d) o[d] = 0.f;
    const uint2* arow = (const uint2*)(S + wq * 132);
#pragma unroll
    for (int c = 0; c < 32; ++c) {
      uint2 u = arow[c];
      float a0 = bfu(u.x & 0xffff), a1 = bfu(u.x >> 16), a2 = bfu(u.y & 0xffff), a3 = bfu(u.y >> 16);
      float aa[4] = {a0, a1, a2, a3};
#pragma unroll
      for (int jj = 0; jj < 4; ++jj) {
        int wk = c * 4 + jj;
        const uint2* vp = (const uint2*)(vs + wk * 36 + dh * 16);
        float av = aa[jj];
#pragma unroll
        for (int c2 = 0; c2 < 4; ++c2) {
          uint2 uv = vp[c2];
          o[c2 * 4 + 0] += av * bfu(uv.x & 0xffff);
          o[c2 * 4 + 1] += av * bfu(uv.x >> 16);
          o[c2 * 4 + 2] += av * bfu(uv.y & 0xffff);
          o[c2 * 4 + 3] += av * bfu(uv.y >> 16);
        }
      }
    }
    __hip_bfloat16* op = att_out + ((size_t)((b * cH + h) * cW + wq)) * cC + g * cHS + dh * 16;
#pragma unroll
    for (int d = 0; d < 16; ++d) op[d] = __float2bfloat16(o[d]);
  }
}

// ---------------- generic bf16 MFMA GEMM: C = A[M,K] @ Bt[N,K]^T, fused epilogues ----------------
// EPI 0: + bias + left^T residual -> bf16 (pre-LN1)
// EPI 1: + bias -> exact GELU -> bf16 (ffn hidden)
// EPI 2: + bias + x1 residual -> bf16 (pre-LN2)
template<int EPI>
__global__ __launch_bounds__(256) void gemm_kernel(
    const __hip_bfloat16* __restrict__ A, const __hip_bfloat16* __restrict__ Bt,
    const int K, const int N,
    const float* __restrict__ bias, const float* __restrict__ leftres,
    const __hip_bfloat16* __restrict__ x1res,
    __hip_bfloat16* __restrict__ outb)
{
  __shared__ __align__(16) __hip_bfloat16 As[64][40];
  __shared__ __align__(16) __hip_bfloat16 Bs[64][40];
  const int m0 = blockIdx.y * 64, n0 = blockIdx.x * 64;
  const int t = threadIdx.x;
  const int srow = t >> 2, skc = (t & 3) << 3;
  const int lane = t & 63, wid = t >> 6;
  const int wr = (wid >> 1) * 32, wc = (wid & 1) * 32;
  const int r16 = lane & 15, kq = lane >> 4;
  f32x4_t acc00 = {0, 0, 0, 0}, acc01 = {0, 0, 0, 0}, acc10 = {0, 0, 0, 0}, acc11 = {0, 0, 0, 0};
  const __hip_bfloat16* aptr = A  + (size_t)(m0 + srow) * K + skc;
  const __hip_bfloat16* bptr = Bt + (size_t)(n0 + srow) * K + skc;
  for (int k0 = 0; k0 < K; k0 += 32) {
    *(int4*)&As[srow][skc] = *(const int4*)(aptr + k0);
    *(int4*)&Bs[srow][skc] = *(const int4*)(bptr + k0);
    __syncthreads();
    bf16x8_t a0 = *(const bf16x8_t*)&As[wr + r16][kq * 8];
    bf16x8_t a1 = *(const bf16x8_t*)&As[wr + 16 + r16][kq * 8];
    bf16x8_t b0 = *(const bf16x8_t*)&Bs[wc + r16][kq * 8];
    bf16x8_t b1 = *(const bf16x8_t*)&Bs[wc + 16 + r16][kq * 8];
    acc00 = __builtin_amdgcn_mfma_f32_16x16x32_bf16(a0, b0, acc00, 0, 0, 0);
    acc01 = __builtin_amdgcn_mfma_f32_16x16x32_bf16(a0, b1, acc01, 0, 0, 0);
    acc10 = __builtin_amdgcn_mfma_f32_16x16x32_bf16(a1, b0, acc10, 0, 0, 0);
    acc11 = __builtin_amdgcn_mfma_f32_16x16x32_bf16(a1, b1, acc11, 0, 0, 0);
    __syncthreads();
  }
#pragma unroll
  for (int fi = 0; fi < 2; ++fi)
#pragma unroll
    for (int fj = 0; fj < 2; ++fj) {
      f32x4_t ac = (fi == 0) ? (fj == 0 ? acc00 : acc01) : (fj == 0 ? acc10 : acc11);
      int nn = n0 + wc + fj * 16 + r16;
#pragma unroll
      for (int r = 0; r < 4; ++r) {
        int mm = m0 + wr + fi * 16 + kq * 4 + r;
        float val = ac[r] + bias[nn];
        if (EPI == 0) {
          int bb = mm >> 15, rem = mm & 32767, hh = rem >> 7, ww = rem & 127;
          val += leftres[(((size_t)bb * 256 + nn) * 256 + hh) * 128 + ww];
          outb[(size_t)mm * N + nn] = __float2bfloat16(val);
        } else if (EPI == 1) {
          val = 0.5f * val * (1.0f + erff(val * 0.7071067811865475f));
          outb[(size_t)mm * N + nn] = __float2bfloat16(val);
        } else {
          val += __bfloat162float(x1res[(size_t)mm * 256 + nn]);
          outb[(size_t)mm * N + nn] = __float2bfloat16(val);
        }
      }
    }
}

// ---------------- LayerNorm over C=256, one wave per row ----------------
// bf16 in -> bf16 (F32OUT=false) or fp32 (F32OUT=true) out; bf16 path may be in-place
template<bool F32OUT>
__global__ __launch_bounds__(256) void ln_kernel(const __hip_bfloat16* __restrict__ in,
                                                 void* __restrict__ outp,
                                                 const float* __restrict__ g,
                                                 const float* __restrict__ b) {
  int row = blockIdx.x * 4 + (threadIdx.x >> 6);
  int lane = threadIdx.x & 63;
  uint2 u = ((const uint2*)in)[(size_t)row * 64 + lane];
  float v[4] = { bfu(u.x & 0xffff), bfu(u.x >> 16), bfu(u.y & 0xffff), bfu(u.y >> 16) };
  float s = v[0] + v[1] + v[2] + v[3];
#pragma unroll
  for (int off = 1; off < 64; off <<= 1) s += __shfl_xor(s, off);
  float mu = s * (1.0f / 256.0f);
  float d0 = v[0] - mu, d1 = v[1] - mu, d2 = v[2] - mu, d3 = v[3] - mu;
  float sq = d0 * d0 + d1 * d1 + d2 * d2 + d3 * d3;
#pragma unroll
  for (int off = 1; off < 64; off <<= 1) sq += __shfl_xor(sq, off);
  float r = rsqrtf(sq * (1.0f / 256.0f) + 1e-5f);
  int col = lane * 4;
  float o0 = d0 * r * g[col + 0] + b[col + 0];
  float o1 = d1 * r * g[col + 1] + b[col + 1];
  float o2 = d2 * r * g[col + 2] + b[col + 2];
  float o3 = d3 * r * g[col + 3] + b[col + 3];
  if (F32OUT) {
    float4 of = make_float4(o0, o1, o2, o3);
    ((float4*)outp)[(size_t)row * 64 + lane] = of;
  } else {
    uint2 ou;
    ou.x = (unsigned)f2bb(o0) | ((unsigned)f2bb(o1) << 16);
    ou.y = (unsigned)f2bb(o2) | ((unsigned)f2bb(o3) << 16);
    ((uint2*)outp)[(size_t)row * 64 + lane] = ou;
  }
}

extern "C" void kernel_launch(void* const* d_in, const int* in_sizes, int n_in,
                              void* d_out, int out_size, void* d_ws, size_t ws_size,
                              hipStream_t stream) {
  const float* left   = (const float*)d_in[0];
  const float* right  = (const float*)d_in[1];
  const float* qw     = (const float*)d_in[2];
  const float* kw     = (const float*)d_in[3];
  const float* vw     = (const float*)d_in[4];
  const float* proj_w = (const float*)d_in[5];
  const float* proj_b = (const float*)d_in[6];
  const float* ln1_g  = (const float*)d_in[7];
  const float* ln1_b  = (const float*)d_in[8];
  const float* ln2_g  = (const float*)d_in[9];
  const float* ln2_b  = (const float*)d_in[10];
  const float* w1     = (const float*)d_in[11];
  const float* b1     = (const float*)d_in[12];
  const float* w2     = (const float*)d_in[13];
  const float* b2     = (const float*)d_in[14];

  char* ws = (char*)d_ws;
  // layout: hidden [M,1024] bf16 at 0 (att_out [M,256] bf16 overlaps it: disjoint lifetimes)
  __hip_bfloat16* hidden  = (__hip_bfloat16*)ws;
  __hip_bfloat16* att_out = (__hip_bfloat16*)ws;
  __hip_bfloat16* x1      = (__hip_bfloat16*)(ws + 268435456);   // [M,256] bf16
  __hip_bfloat16* pre2    = (__hip_bfloat16*)(ws + 335544320);   // [M,256] bf16
  __hip_bfloat16* pwT     = (__hip_bfloat16*)(ws + 402653184);   // [256][256]
  __hip_bfloat16* w1T     = pwT + 65536;                         // [1024][256]
  __hip_bfloat16* w2T     = w1T + 262144;                        // [256][1024]

  transpose_bf16<<<256, 256, 0, stream>>>(proj_w, pwT, 256, 256);
  transpose_bf16<<<1024, 256, 0, stream>>>(w1, w1T, 256, 1024);
  transpose_bf16<<<1024, 256, 0, stream>>>(w2, w2T, 1024, 256);

  attn_kernel<<<cB * cH * cHN, 256, 0, stream>>>(left, right, qw, kw, vw, att_out);

  // x1_pre = att_out @ proj_w + proj_b + left^T
  gemm_kernel<0><<<dim3(4, 2048), 256, 0, stream>>>(att_out, pwT, 256, 256, proj_b, left, nullptr, x1);
  // x1 = LN1(x1_pre), in place
  ln_kernel<false><<<32768, 256, 0, stream>>>(x1, x1, ln1_g, ln1_b);
  // hidden = gelu(x1 @ w1 + b1)
  gemm_kernel<1><<<dim3(16, 2048), 256, 0, stream>>>(x1, w1T, 256, 1024, b1, nullptr, nullptr, hidden);
  // pre2 = hidden @ w2 + b2 + x1
  gemm_kernel<2><<<dim3(4, 2048), 256, 0, stream>>>(hidden, w2T, 1024, 256, b2, nullptr, x1, pre2);
  // out = LN2(pre2)  — d_out is fp32 (reference output dtype is float32)
  ln_kernel<true><<<32768, 256, 0, stream>>>(pre2, d_out, ln2_g, ln2_b);
}

// Round 3
// 731.839 us; speedup vs baseline: 3.3375x; 3.3375x over previous
//
#include <hip/hip_runtime.h>
#include <hip/hip_bf16.h>

#define DEV __device__ __forceinline__

typedef __attribute__((ext_vector_type(8))) short bf16x8_t;
typedef __attribute__((ext_vector_type(4))) float f32x4_t;

constexpr int cB = 4, cC = 256, cH = 256, cW = 128, cHN = 8, cHS = 32;
constexpr int cM = cB * cH * cW;  // 131072 rows

DEV float bfu(unsigned int b16) { union { unsigned int u; float f; } v; v.u = b16 << 16; return v.f; }
DEV unsigned short f2bb(float f) { union { __hip_bfloat16 h; unsigned short u; } v; v.h = __float2bfloat16(f); return v.u; }
DEV unsigned int pk2(float a, float b) { return (unsigned)f2bb(a) | ((unsigned)f2bb(b) << 16); }

// ---------------- weight transpose + fp32->bf16 ----------------
__global__ __launch_bounds__(256) void transpose_bf16(const float* __restrict__ src,
                                                      __hip_bfloat16* __restrict__ dst,
                                                      int R, int Ccol) {
  int idx = blockIdx.x * 256 + threadIdx.x;
  if (idx < R * Ccol) {
    int r = idx / Ccol, c = idx - r * Ccol;
    dst[c * R + r] = __float2bfloat16(src[idx]);
  }
}

// ---------------- MFMA attention: grouped proj + RoPE + softpick + PV ----------------
// one block per (b, h, g); 256 threads = 4 waves, each wave owns 32 q-rows.
// LDS layout (bytes), stride X/Q/K rows = 40 elems (80B), V^T/P rows = 136 elems (272B):
//   XL [0,10240)  XR [10240,20480)  WQ [20480,23040)  WK [23040,25600)  WV [25600,28160)
//   QS [28160,38400)  KS [38400,48640)
//   VT [0,8704) overlays XL (dead after QK-proj);  P [10240,45056) overlays XR..KS (dead after B3)
constexpr int XL_OFF = 0, XR_OFF = 10240, WQ_OFF = 20480, WK_OFF = 23040, WV_OFF = 25600;
constexpr int QS_OFF = 28160, KS_OFF = 38400, VT_OFF = 0, P_OFF = 10240;
constexpr int SMEM_BYTES = 48640;

__global__ __launch_bounds__(256) void attn_mfma(
    const float* __restrict__ left, const float* __restrict__ right,
    const float* __restrict__ qw, const float* __restrict__ kw, const float* __restrict__ vw,
    __hip_bfloat16* __restrict__ att_out)
{
  __shared__ __align__(16) char smem[SMEM_BYTES];
  unsigned short* lds = (unsigned short*)smem;

  const int t = threadIdx.x;
  const int g = blockIdx.x & 7;
  const int h = (blockIdx.x >> 3) & 255;
  const int b = blockIdx.x >> 11;
  const size_t HW = (size_t)cH * cW;

  // ---- stage X (transposed, bf16) and weights ----
  {
    const float* lb = left  + ((size_t)(b * cC + g * cHS) * cH + h) * cW;
    const float* rb = right + ((size_t)(b * cC + g * cHS) * cH + h) * cW;
    int w = t & 127, ih = (t >> 7) * 16;
    unsigned short* xlrow = (unsigned short*)(smem + XL_OFF) + w * 40 + ih;
    unsigned short* xrrow = (unsigned short*)(smem + XR_OFF) + w * 40 + ih;
#pragma unroll
    for (int i = 0; i < 16; i += 2) {
      float a0 = lb[(size_t)(ih + i) * HW + w], a1 = lb[(size_t)(ih + i + 1) * HW + w];
      *(unsigned int*)(xlrow + i) = pk2(a0, a1);
      float c0 = rb[(size_t)(ih + i) * HW + w], c1 = rb[(size_t)(ih + i + 1) * HW + w];
      *(unsigned int*)(xrrow + i) = pk2(c0, c1);
    }
    // weights: thread t loads 4 consecutive floats of each W matrix (row o, cols i0..i0+3)
    int o = t >> 3, i0 = (t & 7) * 4;
    {
      float4 v4 = *(const float4*)(qw + g * 1024 + t * 4);
      unsigned short* dst = (unsigned short*)(smem + WQ_OFF) + o * 40 + i0;
      *(unsigned int*)(dst) = pk2(v4.x, v4.y); *(unsigned int*)(dst + 2) = pk2(v4.z, v4.w);
    }
    {
      float4 v4 = *(const float4*)(kw + g * 1024 + t * 4);
      unsigned short* dst = (unsigned short*)(smem + WK_OFF) + o * 40 + i0;
      *(unsigned int*)(dst) = pk2(v4.x, v4.y); *(unsigned int*)(dst + 2) = pk2(v4.z, v4.w);
    }
    {
      float4 v4 = *(const float4*)(vw + g * 1024 + t * 4);
      unsigned short* dst = (unsigned short*)(smem + WV_OFF) + o * 40 + i0;
      *(unsigned int*)(dst) = pk2(v4.x, v4.y); *(unsigned int*)(dst + 2) = pk2(v4.z, v4.w);
    }
  }
  __syncthreads();  // B1

  const int lane = t & 63, wid = t >> 6;
  const int c = lane & 15, q4 = lane >> 4;
  const int wbase = wid * 32;
  const f32x4_t zero = {0.f, 0.f, 0.f, 0.f};

  // ---- QK projection (MFMA) + RoPE; write qs/ks ----
  bf16x8_t a_xl[2], a_xr[2];
#pragma unroll
  for (int sub = 0; sub < 2; ++sub) {
    a_xl[sub] = *(const bf16x8_t*)(smem + XL_OFF + (wbase + sub * 16 + c) * 80 + q4 * 16);
    a_xr[sub] = *(const bf16x8_t*)(smem + XR_OFF + (wbase + sub * 16 + c) * 80 + q4 * 16);
  }
  f32x4_t qacc[2][2], kacc[2][2];
#pragma unroll
  for (int ot = 0; ot < 2; ++ot) {
    bf16x8_t bq = *(const bf16x8_t*)(smem + WQ_OFF + (ot * 16 + c) * 80 + q4 * 16);
    bf16x8_t bk = *(const bf16x8_t*)(smem + WK_OFF + (ot * 16 + c) * 80 + q4 * 16);
#pragma unroll
    for (int sub = 0; sub < 2; ++sub) {
      qacc[sub][ot] = __builtin_amdgcn_mfma_f32_16x16x32_bf16(a_xl[sub], bq, zero, 0, 0, 0);
      kacc[sub][ot] = __builtin_amdgcn_mfma_f32_16x16x32_bf16(a_xr[sub], bk, zero, 0, 0, 0);
    }
  }
  {
    const float scale = 0.17677669529663687f;  // 1/sqrt(32)
    float inv = expf((float)c * -0.28782313662425572f);  // 100^(-c/16)
    unsigned short* qsp = (unsigned short*)(smem + QS_OFF);
    unsigned short* ksp = (unsigned short*)(smem + KS_OFF);
#pragma unroll
    for (int sub = 0; sub < 2; ++sub)
#pragma unroll
      for (int r = 0; r < 4; ++r) {
        int w = wbase + sub * 16 + q4 * 4 + r;
        float ang = (float)w * inv;
        float sn = sinf(ang), cs = cosf(ang);
        float q0 = qacc[sub][0][r], q1 = qacc[sub][1][r];
        qsp[w * 40 + c]      = f2bb((q0 * cs - q1 * sn) * scale);
        qsp[w * 40 + c + 16] = f2bb((q1 * cs + q0 * sn) * scale);
        float k0 = kacc[sub][0][r], k1 = kacc[sub][1][r];
        ksp[w * 40 + c]      = f2bb(k0 * cs - k1 * sn);
        ksp[w * 40 + c + 16] = f2bb(k1 * cs + k0 * sn);
      }
  }
  __syncthreads();  // B2: qs/ks visible; XL reads complete (vT may overlay XL)

  // ---- V^T projection (MFMA, swapped operands -> transposed output), write vT ----
  {
    f32x4_t vacc[2][2];
#pragma unroll
    for (int dt = 0; dt < 2; ++dt) {
      bf16x8_t awv = *(const bf16x8_t*)(smem + WV_OFF + (dt * 16 + c) * 80 + q4 * 16);
#pragma unroll
      for (int sub = 0; sub < 2; ++sub)
        vacc[dt][sub] = __builtin_amdgcn_mfma_f32_16x16x32_bf16(awv, a_xr[sub], zero, 0, 0, 0);
    }
    unsigned short* vtp = (unsigned short*)(smem + VT_OFF);
#pragma unroll
    for (int dt = 0; dt < 2; ++dt)
#pragma unroll
      for (int sub = 0; sub < 2; ++sub)
#pragma unroll
        for (int r = 0; r < 4; ++r) {
          int d = dt * 16 + q4 * 4 + r;
          int wp = wbase + sub * 16 + c;
          vtp[d * 136 + wp] = f2bb(vacc[dt][sub][r]);
        }
  }

  // ---- S = Q' K'^T (MFMA) ----
  bf16x8_t aq0 = *(const bf16x8_t*)(smem + QS_OFF + (wbase + c) * 80 + q4 * 16);
  bf16x8_t aq1 = *(const bf16x8_t*)(smem + QS_OFF + (wbase + 16 + c) * 80 + q4 * 16);
  f32x4_t sac[2][8];
#pragma unroll
  for (int kt = 0; kt < 8; ++kt) {
    bf16x8_t bk = *(const bf16x8_t*)(smem + KS_OFF + (kt * 16 + c) * 80 + q4 * 16);
    sac[0][kt] = __builtin_amdgcn_mfma_f32_16x16x32_bf16(aq0, bk, zero, 0, 0, 0);
    sac[1][kt] = __builtin_amdgcn_mfma_f32_16x16x32_bf16(aq1, bk, zero, 0, 0, 0);
  }

  // ---- softpick (rows live in 16-lane groups; shfl_xor 1/2/4/8 reduces) ----
  float dinv_[2][4];
#pragma unroll
  for (int sub = 0; sub < 2; ++sub)
#pragma unroll
    for (int r = 0; r < 4; ++r) {
      float m = sac[sub][0][r];
#pragma unroll
      for (int kt = 1; kt < 8; ++kt) m = fmaxf(m, sac[sub][kt][r]);
      m = fmaxf(m, __shfl_xor(m, 1));
      m = fmaxf(m, __shfl_xor(m, 2));
      m = fmaxf(m, __shfl_xor(m, 4));
      m = fmaxf(m, __shfl_xor(m, 8));
      float em = expf(-m);
      float ss = 0.f;
#pragma unroll
      for (int kt = 0; kt < 8; ++kt) {
        float e = expf(sac[sub][kt][r] - m) - em;
        sac[sub][kt][r] = fmaxf(e, 0.f);
        ss += fabsf(e);
      }
      ss += __shfl_xor(ss, 1);
      ss += __shfl_xor(ss, 2);
      ss += __shfl_xor(ss, 4);
      ss += __shfl_xor(ss, 8);
      dinv_[sub][r] = 1.0f / (ss + 1e-6f);
    }
  __syncthreads();  // B3: all qs/ks/wv reads + vT writes complete; P may overlay XR..KS

  // ---- write P (bf16), then PV (MFMA) ----
  {
    unsigned short* pp = (unsigned short*)(smem + P_OFF);
#pragma unroll
    for (int sub = 0; sub < 2; ++sub)
#pragma unroll
      for (int r = 0; r < 4; ++r) {
        int w = wbase + sub * 16 + q4 * 4 + r;
        float dv = dinv_[sub][r];
#pragma unroll
        for (int kt = 0; kt < 8; ++kt)
          pp[w * 136 + kt * 16 + c] = f2bb(sac[sub][kt][r] * dv);
      }
  }
  f32x4_t oacc[2][2] = {{zero, zero}, {zero, zero}};
#pragma unroll
  for (int ks = 0; ks < 4; ++ks) {
    bf16x8_t ap0 = *(const bf16x8_t*)(smem + P_OFF + (wbase + c) * 272 + ks * 64 + q4 * 16);
    bf16x8_t ap1 = *(const bf16x8_t*)(smem + P_OFF + (wbase + 16 + c) * 272 + ks * 64 + q4 * 16);
    bf16x8_t bv0 = *(const bf16x8_t*)(smem + VT_OFF + (c) * 272 + ks * 64 + q4 * 16);
    bf16x8_t bv1 = *(const bf16x8_t*)(smem + VT_OFF + (16 + c) * 272 + ks * 64 + q4 * 16);
    oacc[0][0] = __builtin_amdgcn_mfma_f32_16x16x32_bf16(ap0, bv0, oacc[0][0], 0, 0, 0);
    oacc[0][1] = __builtin_amdgcn_mfma_f32_16x16x32_bf16(ap0, bv1, oacc[0][1], 0, 0, 0);
    oacc[1][0] = __builtin_amdgcn_mfma_f32_16x16x32_bf16(ap1, bv0, oacc[1][0], 0, 0, 0);
    oacc[1][1] = __builtin_amdgcn_mfma_f32_16x16x32_bf16(ap1, bv1, oacc[1][1], 0, 0, 0);
  }
  // ---- epilogue: O[w, d] -> att_out[(b,h,w), g*32+d] ----
  {
    __hip_bfloat16* ob = att_out + ((size_t)(b * cH + h) * cW) * cC + g * cHS;
#pragma unroll
    for (int sub = 0; sub < 2; ++sub)
#pragma unroll
      for (int dt = 0; dt < 2; ++dt)
#pragma unroll
        for (int r = 0; r < 4; ++r) {
          int w = wbase + sub * 16 + q4 * 4 + r;
          ob[(size_t)w * cC + dt * 16 + c] = __float2bfloat16(oacc[sub][dt][r]);
        }
  }
}

// ---------------- generic bf16 MFMA GEMM: C = A[M,K] @ Bt[N,K]^T, fused epilogues ----------------
// EPI 0: + bias + left^T residual -> bf16 (pre-LN1)
// EPI 1: + bias -> exact GELU -> bf16 (ffn hidden)
// EPI 2: + bias + x1 residual -> bf16 (pre-LN2)
template<int EPI>
__global__ __launch_bounds__(256) void gemm_kernel(
    const __hip_bfloat16* __restrict__ A, const __hip_bfloat16* __restrict__ Bt,
    const int K, const int N,
    const float* __restrict__ bias, const float* __restrict__ leftres,
    const __hip_bfloat16* __restrict__ x1res,
    __hip_bfloat16* __restrict__ outb)
{
  __shared__ __align__(16) __hip_bfloat16 As[64][40];
  __shared__ __align__(16) __hip_bfloat16 Bs[64][40];
  const int m0 = blockIdx.y * 64, n0 = blockIdx.x * 64;
  const int t = threadIdx.x;
  const int srow = t >> 2, skc = (t & 3) << 3;
  const int lane = t & 63, wid = t >> 6;
  const int wr = (wid >> 1) * 32, wc = (wid & 1) * 32;
  const int r16 = lane & 15, kq = lane >> 4;
  f32x4_t acc00 = {0, 0, 0, 0}, acc01 = {0, 0, 0, 0}, acc10 = {0, 0, 0, 0}, acc11 = {0, 0, 0, 0};
  const __hip_bfloat16* aptr = A  + (size_t)(m0 + srow) * K + skc;
  const __hip_bfloat16* bptr = Bt + (size_t)(n0 + srow) * K + skc;
  for (int k0 = 0; k0 < K; k0 += 32) {
    *(int4*)&As[srow][skc] = *(const int4*)(aptr + k0);
    *(int4*)&Bs[srow][skc] = *(const int4*)(bptr + k0);
    __syncthreads();
    bf16x8_t a0 = *(const bf16x8_t*)&As[wr + r16][kq * 8];
    bf16x8_t a1 = *(const bf16x8_t*)&As[wr + 16 + r16][kq * 8];
    bf16x8_t b0 = *(const bf16x8_t*)&Bs[wc + r16][kq * 8];
    bf16x8_t b1 = *(const bf16x8_t*)&Bs[wc + 16 + r16][kq * 8];
    acc00 = __builtin_amdgcn_mfma_f32_16x16x32_bf16(a0, b0, acc00, 0, 0, 0);
    acc01 = __builtin_amdgcn_mfma_f32_16x16x32_bf16(a0, b1, acc01, 0, 0, 0);
    acc10 = __builtin_amdgcn_mfma_f32_16x16x32_bf16(a1, b0, acc10, 0, 0, 0);
    acc11 = __builtin_amdgcn_mfma_f32_16x16x32_bf16(a1, b1, acc11, 0, 0, 0);
    __syncthreads();
  }
#pragma unroll
  for (int fi = 0; fi < 2; ++fi)
#pragma unroll
    for (int fj = 0; fj < 2; ++fj) {
      f32x4_t ac = (fi == 0) ? (fj == 0 ? acc00 : acc01) : (fj == 0 ? acc10 : acc11);
      int nn = n0 + wc + fj * 16 + r16;
#pragma unroll
      for (int r = 0; r < 4; ++r) {
        int mm = m0 + wr + fi * 16 + kq * 4 + r;
        float val = ac[r] + bias[nn];
        if (EPI == 0) {
          int bb = mm >> 15, rem = mm & 32767, hh = rem >> 7, ww = rem & 127;
          val += leftres[(((size_t)bb * 256 + nn) * 256 + hh) * 128 + ww];
          outb[(size_t)mm * N + nn] = __float2bfloat16(val);
        } else if (EPI == 1) {
          val = 0.5f * val * (1.0f + erff(val * 0.7071067811865475f));
          outb[(size_t)mm * N + nn] = __float2bfloat16(val);
        } else {
          val += __bfloat162float(x1res[(size_t)mm * 256 + nn]);
          outb[(size_t)mm * N + nn] = __float2bfloat16(val);
        }
      }
    }
}

// ---------------- LayerNorm over C=256, one wave per row ----------------
// bf16 in -> bf16 (F32OUT=false) or fp32 (F32OUT=true) out; bf16 path may be in-place
template<bool F32OUT>
__global__ __launch_bounds__(256) void ln_kernel(const __hip_bfloat16* __restrict__ in,
                                                 void* __restrict__ outp,
                                                 const float* __restrict__ g,
                                                 const float* __restrict__ b) {
  int row = blockIdx.x * 4 + (threadIdx.x >> 6);
  int lane = threadIdx.x & 63;
  uint2 u = ((const uint2*)in)[(size_t)row * 64 + lane];
  float v[4] = { bfu(u.x & 0xffff), bfu(u.x >> 16), bfu(u.y & 0xffff), bfu(u.y >> 16) };
  float s = v[0] + v[1] + v[2] + v[3];
#pragma unroll
  for (int off = 1; off < 64; off <<= 1) s += __shfl_xor(s, off);
  float mu = s * (1.0f / 256.0f);
  float d0 = v[0] - mu, d1 = v[1] - mu, d2 = v[2] - mu, d3 = v[3] - mu;
  float sq = d0 * d0 + d1 * d1 + d2 * d2 + d3 * d3;
#pragma unroll
  for (int off = 1; off < 64; off <<= 1) sq += __shfl_xor(sq, off);
  float r = rsqrtf(sq * (1.0f / 256.0f) + 1e-5f);
  int col = lane * 4;
  float o0 = d0 * r * g[col + 0] + b[col + 0];
  float o1 = d1 * r * g[col + 1] + b[col + 1];
  float o2 = d2 * r * g[col + 2] + b[col + 2];
  float o3 = d3 * r * g[col + 3] + b[col + 3];
  if (F32OUT) {
    float4 of = make_float4(o0, o1, o2, o3);
    ((float4*)outp)[(size_t)row * 64 + lane] = of;
  } else {
    uint2 ou;
    ou.x = (unsigned)f2bb(o0) | ((unsigned)f2bb(o1) << 16);
    ou.y = (unsigned)f2bb(o2) | ((unsigned)f2bb(o3) << 16);
    ((uint2*)outp)[(size_t)row * 64 + lane] = ou;
  }
}

extern "C" void kernel_launch(void* const* d_in, const int* in_sizes, int n_in,
                              void* d_out, int out_size, void* d_ws, size_t ws_size,
                              hipStream_t stream) {
  const float* left   = (const float*)d_in[0];
  const float* right  = (const float*)d_in[1];
  const float* qw     = (const float*)d_in[2];
  const float* kw     = (const float*)d_in[3];
  const float* vw     = (const float*)d_in[4];
  const float* proj_w = (const float*)d_in[5];
  const float* proj_b = (const float*)d_in[6];
  const float* ln1_g  = (const float*)d_in[7];
  const float* ln1_b  = (const float*)d_in[8];
  const float* ln2_g  = (const float*)d_in[9];
  const float* ln2_b  = (const float*)d_in[10];
  const float* w1     = (const float*)d_in[11];
  const float* b1     = (const float*)d_in[12];
  const float* w2     = (const float*)d_in[13];
  const float* b2     = (const float*)d_in[14];

  char* ws = (char*)d_ws;
  // layout: hidden [M,1024] bf16 at 0 (att_out [M,256] bf16 overlaps it: disjoint lifetimes)
  __hip_bfloat16* hidden  = (__hip_bfloat16*)ws;
  __hip_bfloat16* att_out = (__hip_bfloat16*)ws;
  __hip_bfloat16* x1      = (__hip_bfloat16*)(ws + 268435456);   // [M,256] bf16
  __hip_bfloat16* pre2    = (__hip_bfloat16*)(ws + 335544320);   // [M,256] bf16
  __hip_bfloat16* pwT     = (__hip_bfloat16*)(ws + 402653184);   // [256][256]
  __hip_bfloat16* w1T     = pwT + 65536;                         // [1024][256]
  __hip_bfloat16* w2T     = w1T + 262144;                        // [256][1024]

  transpose_bf16<<<256, 256, 0, stream>>>(proj_w, pwT, 256, 256);
  transpose_bf16<<<1024, 256, 0, stream>>>(w1, w1T, 256, 1024);
  transpose_bf16<<<1024, 256, 0, stream>>>(w2, w2T, 1024, 256);

  attn_mfma<<<cB * cH * cHN, 256, 0, stream>>>(left, right, qw, kw, vw, att_out);

  // x1_pre = att_out @ proj_w + proj_b + left^T
  gemm_kernel<0><<<dim3(4, 2048), 256, 0, stream>>>(att_out, pwT, 256, 256, proj_b, left, nullptr, x1);
  // x1 = LN1(x1_pre), in place
  ln_kernel<false><<<32768, 256, 0, stream>>>(x1, x1, ln1_g, ln1_b);
  // hidden = gelu(x1 @ w1 + b1)
  gemm_kernel<1><<<dim3(16, 2048), 256, 0, stream>>>(x1, w1T, 256, 1024, b1, nullptr, nullptr, hidden);
  // pre2 = hidden @ w2 + b2 + x1
  gemm_kernel<2><<<dim3(4, 2048), 256, 0, stream>>>(hidden, w2T, 1024, 256, b2, nullptr, x1, pre2);
  // out = LN2(pre2)  — d_out is fp32 (reference output dtype is float32)
  ln_kernel<true><<<32768, 256, 0, stream>>>(pre2, d_out, ln2_g, ln2_b);
}